// Round 12
// baseline (521.259 us; speedup 1.0000x reference)
//
#include <hip/hip_runtime.h>
#include <math.h>

#define BB 64
#define N1 512
#define K1 256
#define K2 128
#define HF 128   // feature dim
#define NC 10

// XCD-aware bijective swizzle: contiguous 1/8 chunks of the grid per XCD.
__device__ __forceinline__ int xcd_swizzle(int bid, int nwg) {
    return (bid & 7) * (nwg >> 3) + (bid >> 3);
}

// ---------------------------------------------------------------------------
// degree + bitset + CSR-value kernel: one wave per row.
// Writes dinv (= deg>0 ? 1/sqrt(deg) : 0) directly instead of deg.
// dinv_gcn uses deg+ (diag==0?1:0); dinv_info uses raw rowsum.
// ---------------------------------------------------------------------------
__global__ __launch_bounds__(64) void deg_bits_kernel(const float* __restrict__ adj,
                                                      float* __restrict__ dinv_gcn,
                                                      float* __restrict__ dinv_info,
                                                      unsigned* __restrict__ bits,
                                                      float* __restrict__ adjval, int n) {
    int row = blockIdx.x;              // b*n + i
    int i = row % n;
    const float* ar = adj + (size_t)row * n;
    float* av = adjval + (size_t)row * n;
    int lane = threadIdx.x;            // 64
    int W = n >> 5;
    unsigned* wrow = bits + (size_t)row * W;
    float s = 0.f;
    int base = 0;
    int kn = n >> 6;
    for (int k = 0; k < kn; k++) {
        float a = ar[k * 64 + lane];
        s += a;
        unsigned long long m = __ballot(a > 0.f);
        if (lane == 0) {
            wrow[2 * k]     = (unsigned)(m & 0xffffffffull);
            wrow[2 * k + 1] = (unsigned)(m >> 32);
        }
        if (a > 0.f) {
            int slot = base + (int)__popcll(m & ((1ull << lane) - 1ull));
            av[slot] = a;
        }
        base += (int)__popcll(m);
    }
    for (int off = 32; off > 0; off >>= 1) s += __shfl_down(s, off);
    if (lane == 0) {
        float diag = ar[i];
        float dg = s + (diag == 0.f ? 1.f : 0.f);
        dinv_info[row] = s  > 0.f ? 1.f / sqrtf(s)  : 0.f;
        dinv_gcn[row]  = dg > 0.f ? 1.f / sqrtf(dg) : 0.f;
    }
}

// ---------------------------------------------------------------------------
// build_coef: one wave per row (4 rows / 256-thr block). Walks bits once:
//   adjval[slot]  <- a * dinv_info[j]   (in-place, slot-exact, read-first)
//   coefg[o]      <- a_aug * dinv_gcn[j]  (augmented slots incl. self)
// Hoists the scattered dinv gathers + muls out of BOTH agg kernels.
// Same float expressions / same ascending-j order -> bit-exact downstream.
// ---------------------------------------------------------------------------
__global__ __launch_bounds__(256) void build_coef(const unsigned* __restrict__ bits,
                                                  float* __restrict__ adjval,
                                                  float* __restrict__ coefg,
                                                  const float* __restrict__ dinvg,
                                                  const float* __restrict__ dinvi,
                                                  int n) {
    int lane = threadIdx.x & 63;
    int row = blockIdx.x * 4 + (threadIdx.x >> 6);
    int b = row / n, i = row % n;
    int W = n >> 5;
    float* av = adjval + (size_t)row * n;
    float* cg = coefg + (size_t)row * n;
    const float* dg = dinvg + b * n;
    const float* di = dinvi + b * n;
    unsigned worig = (lane < W) ? bits[(size_t)row * W + lane] : 0u;
    unsigned w = worig;
    if ((i >> 5) == lane) w |= (1u << (i & 31));
    int pca = __popc(w), pco = __popc(worig);
    int sc = (pca << 16) | pco;
#pragma unroll
    for (int off = 1; off < 64; off <<= 1) {
        int t = __shfl_up(sc, off);
        if (lane >= off) sc += t;
    }
    int o  = (sc >> 16) - pca;
    int cb = (sc & 0xffff) - pco;
    unsigned mm = w;
    while (mm) {
        int bp = __ffs(mm) - 1;
        mm &= mm - 1;
        int j = (lane << 5) + bp;
        float a;
        if ((worig >> bp) & 1u) { a = av[cb]; av[cb] = a * di[j]; cb++; }
        else                    { a = 1.f; }
        cg[o] = a * dg[j];
        o++;
    }
}

// ---------------------------------------------------------------------------
// Y[M,128] = X[M,128] @ W[128,128].
// ---------------------------------------------------------------------------
__global__ __launch_bounds__(128) void gemm128(const float* __restrict__ X,
                                               const float* __restrict__ W,
                                               float* __restrict__ Y, int M) {
    __shared__ float xl[16 * 128];
    int f = threadIdx.x;
    int r0 = blockIdx.x * 16;
    for (int idx = f; idx < 16 * 128; idx += 128) {
        int r = idx >> 7, k = idx & 127;
        xl[idx] = X[(size_t)(r0 + r) * 128 + k];
    }
    __syncthreads();
    float acc[16];
#pragma unroll
    for (int r = 0; r < 16; r++) acc[r] = 0.f;
    for (int k = 0; k < 128; k++) {
        float w = W[k * 128 + f];
#pragma unroll
        for (int r = 0; r < 16; r++) acc[r] += xl[r * 128 + k] * w;
    }
#pragma unroll
    for (int r = 0; r < 16; r++) Y[(size_t)(r0 + r) * 128 + f] = acc[r];
}

// ---------------------------------------------------------------------------
// gcn_agg: walk reads PRE-MULTIPLIED coefs (contiguous) -> no scattered deg
// loads, no rsqrt in the hot path. XCD-swizzled for h L2 locality.
// ---------------------------------------------------------------------------
__global__ __launch_bounds__(128) void gcn_agg(const float* __restrict__ coefg,
                                               const unsigned* __restrict__ bits,
                                               const float* __restrict__ dinvg,
                                               const float* __restrict__ hin,
                                               const float* __restrict__ bias,
                                               float* __restrict__ hout, int n) {
    __shared__ int idxl[512];
    __shared__ float coef[512];
    __shared__ int s_nnz;
    int row = xcd_swizzle(blockIdx.x, gridDim.x);
    int b = row / n, i = row % n;
    int tid = threadIdx.x;
    int W = n >> 5;
    const float* cgrow = coefg + (size_t)row * n;
    if (tid < 64) {
        int lane = tid;
        unsigned w = 0;
        if (lane < W) {
            w = bits[(size_t)row * W + lane];
            if ((i >> 5) == lane) w |= (1u << (i & 31));   // ensure self bit
        }
        int pc = __popc(w);
        int sc = pc;
#pragma unroll
        for (int off = 1; off < 64; off <<= 1) {
            int t = __shfl_up(sc, off);
            if (lane >= off) sc += t;
        }
        if (lane == 63) s_nnz = sc;
        int o = sc - pc;
        unsigned mm = w;
        while (mm) {
            int bp = __ffs(mm) - 1;
            mm &= mm - 1;
            int j = (lane << 5) + bp;
            idxl[o] = j;
            coef[o] = cgrow[o];
            o++;
        }
    }
    __syncthreads();
    int nnz = s_nnz;
    int f = tid;
    const float* hb = hin + (size_t)b * n * HF;
    float acc = 0.f;
    int it = 0;
    for (; it + 4 <= nnz; it += 4) {
        int j0 = idxl[it], j1 = idxl[it + 1], j2 = idxl[it + 2], j3 = idxl[it + 3];
        float v0 = hb[(size_t)j0 * HF + f];
        float v1 = hb[(size_t)j1 * HF + f];
        float v2 = hb[(size_t)j2 * HF + f];
        float v3 = hb[(size_t)j3 * HF + f];
        float c0 = coef[it], c1 = coef[it + 1], c2 = coef[it + 2], c3 = coef[it + 3];
        acc += c0 * v0; acc += c1 * v1; acc += c2 * v2; acc += c3 * v3;
    }
    for (; it < nnz; it++) {
        acc += coef[it] * hb[(size_t)idxl[it] * HF + f];
    }
    float di = dinvg[b * n + i];
    float v = di * acc + bias[f];
    hout[(size_t)row * HF + f] = fmaxf(v, 0.f);
}

__global__ __launch_bounds__(128) void info_score(const float* __restrict__ coefi,
                                                  const unsigned* __restrict__ bits,
                                                  const float* __restrict__ dinvi,
                                                  const float* __restrict__ h,
                                                  float* __restrict__ score, int n) {
    __shared__ int idxl[512];
    __shared__ float coef[512];
    __shared__ int s_nnz;
    __shared__ float red[128];
    int row = xcd_swizzle(blockIdx.x, gridDim.x);
    int b = row / n, i = row % n;
    int tid = threadIdx.x;
    int W = n >> 5;
    const float* cirow = coefi + (size_t)row * n;
    if (tid < 64) {
        int lane = tid;
        unsigned w = (lane < W) ? bits[(size_t)row * W + lane] : 0u;
        int pc = __popc(w);
        int sc = pc;
#pragma unroll
        for (int off = 1; off < 64; off <<= 1) {
            int t = __shfl_up(sc, off);
            if (lane >= off) sc += t;
        }
        if (lane == 63) s_nnz = sc;
        int o = sc - pc;                   // == CSR slot
        unsigned mm = w;
        while (mm) {
            int bp = __ffs(mm) - 1;
            mm &= mm - 1;
            int j = (lane << 5) + bp;
            idxl[o] = j;
            coef[o] = cirow[o];
            o++;
        }
    }
    __syncthreads();
    int nnz = s_nnz;
    int f = tid;
    const float* hb = h + (size_t)b * n * HF;
    float acc = 0.f;
    int it = 0;
    for (; it + 4 <= nnz; it += 4) {
        int j0 = idxl[it], j1 = idxl[it + 1], j2 = idxl[it + 2], j3 = idxl[it + 3];
        float v0 = hb[(size_t)j0 * HF + f];
        float v1 = hb[(size_t)j1 * HF + f];
        float v2 = hb[(size_t)j2 * HF + f];
        float v3 = hb[(size_t)j3 * HF + f];
        float c0 = coef[it], c1 = coef[it + 1], c2 = coef[it + 2], c3 = coef[it + 3];
        acc += c0 * v0; acc += c1 * v1; acc += c2 * v2; acc += c3 * v3;
    }
    for (; it < nnz; it++) {
        acc += coef[it] * hb[(size_t)idxl[it] * HF + f];
    }
    float di = dinvi[b * n + i];
    float diff = fabsf(hb[(size_t)i * HF + f] - di * acc);
    red[f] = diff;
    __syncthreads();
    for (int s = 64; s > 0; s >>= 1) {
        if (f < s) red[f] += red[f + s];
        __syncthreads();
    }
    if (f == 0) score[row] = red[0];
}

// ---------------------------------------------------------------------------
// top-k: per-graph bitonic sort on 64-bit key.
// ---------------------------------------------------------------------------
template <int NN>
__global__ __launch_bounds__(NN) void topk_kernel(const float* __restrict__ score,
                                                  int* __restrict__ perm, int k) {
    __shared__ unsigned long long keys[NN];
    int b = blockIdx.x, t = threadIdx.x;
    unsigned u = __float_as_uint(score[b * NN + t]);
    unsigned asc = (u & 0x80000000u) ? ~u : (u | 0x80000000u); // monotone map
    unsigned desc = ~asc;                                      // larger score -> smaller key
    keys[t] = ((unsigned long long)desc << 32) | (unsigned)t;
    __syncthreads();
    for (int kk = 2; kk <= NN; kk <<= 1) {
        for (int j = kk >> 1; j > 0; j >>= 1) {
            int ixj = t ^ j;
            if (ixj > t) {
                bool up = ((t & kk) == 0);
                unsigned long long a = keys[t], c = keys[ixj];
                if ((a > c) == up) { keys[t] = c; keys[ixj] = a; }
            }
            __syncthreads();
        }
    }
    if (t < k) perm[b * k + t] = (int)(keys[t] & 0xffffffffu);
}

__global__ __launch_bounds__(128) void gather_rows(const float* __restrict__ h,
                                                   const int* __restrict__ perm,
                                                   float* __restrict__ xp, int n, int k) {
    int idx = blockIdx.x;  // b*k + i
    int b = idx / k;
    int f = threadIdx.x;
    int pi = perm[idx];
    xp[(size_t)idx * HF + f] = h[((size_t)b * n + pi) * HF + f];
}

// ---------------------------------------------------------------------------
// bits expansion pass 1 (all rows).
// ---------------------------------------------------------------------------
__global__ __launch_bounds__(64) void bits_expand(const unsigned* __restrict__ sin,
                                                  unsigned* __restrict__ sout, int n, int W) {
    __shared__ unsigned rowi[16];
    __shared__ int jlist[512];
    __shared__ unsigned res[64];
    __shared__ int s_nnz;
    int row = blockIdx.x;
    int b = row / n;
    int t = threadIdx.x;       // 64
    unsigned w = (t < W) ? sin[(size_t)row * W + t] : 0u;
    if (t < W) rowi[t] = w;
    int pc = __popc(w);
    int sc = pc;
#pragma unroll
    for (int off = 1; off < 64; off <<= 1) {
        int v = __shfl_up(sc, off);
        if (t >= off) sc += v;
    }
    if (t == 63) s_nnz = sc;
    int o = sc - pc;
    unsigned mm = w;
    while (mm) {
        int bp = __ffs(mm) - 1;
        mm &= mm - 1;
        jlist[o++] = (t << 5) + bp;
    }
    __syncthreads();
    int nnz = s_nnz;
    int JC = 64 / W;
    int chunk = t / W, wi = t % W;
    const unsigned* sb = sin + (size_t)b * n * W;
    unsigned r = 0;
    int q = chunk;
    for (; q + 3 * JC < nnz; q += 4 * JC) {
        int j0 = jlist[q], j1 = jlist[q + JC], j2 = jlist[q + 2 * JC], j3 = jlist[q + 3 * JC];
        unsigned v0 = sb[(size_t)j0 * W + wi];
        unsigned v1 = sb[(size_t)j1 * W + wi];
        unsigned v2 = sb[(size_t)j2 * W + wi];
        unsigned v3 = sb[(size_t)j3 * W + wi];
        r |= v0 | v1 | v2 | v3;
    }
    for (; q < nnz; q += JC) r |= sb[(size_t)jlist[q] * W + wi];
    res[t] = r;
    __syncthreads();
    if (t < W) {
        unsigned acc = rowi[t];
        for (int c = 0; c < JC; c++) acc |= res[c * W + t];
        sout[(size_t)row * W + t] = acc;
    }
}

// ---------------------------------------------------------------------------
// bits expansion pass 2, perm-compacted.
// ---------------------------------------------------------------------------
__global__ __launch_bounds__(64) void bits_expand_perm(const unsigned* __restrict__ sin,
                                                       const int* __restrict__ perm,
                                                       unsigned* __restrict__ sout,
                                                       int n, int W, int k) {
    __shared__ unsigned rowi[16];
    __shared__ int jlist[512];
    __shared__ unsigned res[64];
    __shared__ int s_nnz;
    int r0 = blockIdx.x;       // b*k + i
    int b = r0 / k;
    int pi = perm[r0];
    int t = threadIdx.x;       // 64
    size_t srow = (size_t)(b * n + pi) * W;
    unsigned w = (t < W) ? sin[srow + t] : 0u;
    if (t < W) rowi[t] = w;
    int pc = __popc(w);
    int sc = pc;
#pragma unroll
    for (int off = 1; off < 64; off <<= 1) {
        int v = __shfl_up(sc, off);
        if (t >= off) sc += v;
    }
    if (t == 63) s_nnz = sc;
    int o = sc - pc;
    unsigned mm = w;
    while (mm) {
        int bp = __ffs(mm) - 1;
        mm &= mm - 1;
        jlist[o++] = (t << 5) + bp;
    }
    __syncthreads();
    int nnz = s_nnz;
    int JC = 64 / W;
    int chunk = t / W, wi = t % W;
    const unsigned* sb = sin + (size_t)b * n * W;
    unsigned r = 0;
    int q = chunk;
    for (; q + 3 * JC < nnz; q += 4 * JC) {
        int j0 = jlist[q], j1 = jlist[q + JC], j2 = jlist[q + 2 * JC], j3 = jlist[q + 3 * JC];
        unsigned v0 = sb[(size_t)j0 * W + wi];
        unsigned v1 = sb[(size_t)j1 * W + wi];
        unsigned v2 = sb[(size_t)j2 * W + wi];
        unsigned v3 = sb[(size_t)j3 * W + wi];
        r |= v0 | v1 | v2 | v3;
    }
    for (; q < nnz; q += JC) r |= sb[(size_t)jlist[q] * W + wi];
    res[t] = r;
    __syncthreads();
    if (t < W) {
        unsigned acc = rowi[t];
        for (int c = 0; c < JC; c++) acc |= res[c * W + t];
        sout[(size_t)r0 * W + t] = acc;
    }
}

// a_i = xp.att[:128], a_j = xp.att[128:]
__global__ __launch_bounds__(128) void attn_dots(const float* __restrict__ xp,
                                                 const float* __restrict__ att,
                                                 float* __restrict__ ai, float* __restrict__ aj) {
    __shared__ float red[128];
    int idx = blockIdx.x;
    int f = threadIdx.x;
    float v = xp[(size_t)idx * HF + f];
    red[f] = v * att[f];
    __syncthreads();
    for (int s = 64; s > 0; s >>= 1) {
        if (f < s) red[f] += red[f + s];
        __syncthreads();
    }
    if (f == 0) ai[idx] = red[0];
    __syncthreads();
    red[f] = v * att[128 + f];
    __syncthreads();
    for (int s = 64; s > 0; s >>= 1) {
        if (f < s) red[f] += red[f + s];
        __syncthreads();
    }
    if (f == 0) aj[idx] = red[0];
}

// ---------------------------------------------------------------------------
// sparsemax, wave-per-row, register-resident, barrier-free.
// ---------------------------------------------------------------------------
template <int K>
__global__ __launch_bounds__(256) void sparsemax_wave(const float* __restrict__ ai,
                                                      const float* __restrict__ aj,
                                                      const int* __restrict__ perm,
                                                      const float* __restrict__ adjprev,
                                                      const unsigned* __restrict__ s4c,
                                                      float* __restrict__ newadj,
                                                      int nprev, int Wprev) {
    constexpr int EPL = K / 64;
    int lane = threadIdx.x & 63;
    int wid = threadIdx.x >> 6;
    int r = blockIdx.x * 4 + wid;      // row id: b*K + i
    int b = r / K, i = r % K;
    int pi = perm[r];
    float air = ai[r];
    const float* aprow = adjprev + ((size_t)b * nprev + pi) * nprev;
    const unsigned* srow = s4c + (size_t)r * Wprev;
    const int* permb = perm + b * K;
    const float* ajb = aj + b * K;

    float z[EPL], zc[EPL], zs[EPL];
    unsigned mbits = 0;
    float m = -1e30f;
#pragma unroll
    for (int e = 0; e < EPL; e++) {
        int j = lane * EPL + e;
        int pj = permb[j];
        float ap = aprow[pj];
        unsigned wb = srow[pj >> 5];
        bool mask = ((wb >> (pj & 31)) & 1u) || (i == j);
        float v = air + ajb[j];
        float lr = v > 0.f ? v : 0.2f * v;
        z[e] = lr + ap;                // LAMB = 1
        if (mask) mbits |= (1u << e);
        m = fmaxf(m, mask ? z[e] : -1e30f);
    }
    // wave allreduce max
#pragma unroll
    for (int off = 1; off < 64; off <<= 1) m = fmaxf(m, __shfl_xor(m, off));

#pragma unroll
    for (int e = 0; e < EPL; e++) {
        zc[e] = z[e] - m;
        zs[e] = ((mbits >> e) & 1u) ? zc[e] : -1e30f;
    }

    // bitonic sort descending over K elements
    for (int kk = 2; kk <= K; kk <<= 1) {
        for (int d = kk >> 1; d >= EPL; d >>= 1) {
            int lm = d / EPL;
#pragma unroll
            for (int e = 0; e < EPL; e++) {
                float other = __shfl_xor(zs[e], lm);
                int idx = lane * EPL + e;
                bool desc = (idx & kk) == 0;
                bool lower = (lane & lm) == 0;
                zs[e] = (desc == lower) ? fmaxf(zs[e], other) : fminf(zs[e], other);
            }
        }
#pragma unroll
        for (int dd = EPL >> 1; dd >= 1; dd >>= 1) {
            if (kk > dd) {
#pragma unroll
                for (int e = 0; e < EPL; e++) {
                    if (!(e & dd)) {
                        int ep = e | dd;
                        int idx = lane * EPL + e;
                        bool desc = (idx & kk) == 0;
                        float a = zs[e], c = zs[ep];
                        float mx = fmaxf(a, c), mn = fminf(a, c);
                        zs[e] = desc ? mx : mn;
                        zs[ep] = desc ? mn : mx;
                    }
                }
            }
        }
    }

    // inclusive cumsum: per-lane sequential + Kogge-Stone lane scan
    float c[EPL];
    c[0] = zs[0];
#pragma unroll
    for (int e = 1; e < EPL; e++) c[e] = c[e - 1] + zs[e];
    float lsum = c[EPL - 1];
    float sc = lsum;
#pragma unroll
    for (int off = 1; off < 64; off <<= 1) {
        float t = __shfl_up(sc, off);
        if (lane >= off) sc += t;
    }
    float excl = sc - lsum;
#pragma unroll
    for (int e = 0; e < EPL; e++) c[e] += excl;   // c[e] = cum at idx lane*EPL+e

    // rho = count of (1 + (idx+1)*zsort > cum)
    int cnt = 0;
#pragma unroll
    for (int e = 0; e < EPL; e++) {
        int idx = lane * EPL + e;
        if (1.f + (float)(idx + 1) * zs[e] > c[e]) cnt++;
    }
#pragma unroll
    for (int off = 1; off < 64; off <<= 1) cnt += __shfl_xor(cnt, off);
    int rho = cnt;

    // cum at index rho-1
    int pos = rho - 1;
    int tl = pos / EPL, te = pos % EPL;
    float g[EPL];
#pragma unroll
    for (int e = 0; e < EPL; e++) g[e] = __shfl(c[e], tl);
    float cum_rho = g[0];
#pragma unroll
    for (int e = 1; e < EPL; e++) cum_rho = (te == e) ? g[e] : cum_rho;
    float tau = (cum_rho - 1.f) / (float)rho;

    float o[EPL];
#pragma unroll
    for (int e = 0; e < EPL; e++)
        o[e] = fmaxf(zc[e] - tau, 0.f) * (((mbits >> e) & 1u) ? 1.f : 0.f);

    float* orow = newadj + (size_t)r * K + lane * EPL;
    if constexpr (EPL == 4) {
        *reinterpret_cast<float4*>(orow) = make_float4(o[0], o[1], o[2], o[3]);
    } else {
        *reinterpret_cast<float2*>(orow) = make_float2(o[0], o[1]);
    }
}

// ---------------------------------------------------------------------------
// readout, two-pass.
// ---------------------------------------------------------------------------
__global__ __launch_bounds__(128) void readout_partial(const float* __restrict__ h,
                                                       float* __restrict__ pmax,
                                                       float* __restrict__ psum,
                                                       int n, int nch) {
    int blk = blockIdx.x;              // b*nch + c
    int c = blk % nch;
    int f = threadIdx.x;
    const float* hb = h + ((size_t)(blk / nch) * n + c * 32) * HF;
    float mx = -INFINITY, sm = 0.f;
#pragma unroll
    for (int i = 0; i < 32; i++) {
        float v = hb[(size_t)i * HF + f];
        mx = fmaxf(mx, v);
        sm += v;
    }
    pmax[(size_t)blk * HF + f] = mx;
    psum[(size_t)blk * HF + f] = sm;
}

__global__ __launch_bounds__(128) void readout_combine(const float* __restrict__ pmax,
                                                       const float* __restrict__ psum,
                                                       float* __restrict__ out,
                                                       int n, int nch) {
    int b = blockIdx.x;
    int f = threadIdx.x;
    float mx = -INFINITY, sm = 0.f;
    for (int c = 0; c < nch; c++) {
        mx = fmaxf(mx, pmax[((size_t)b * nch + c) * HF + f]);
        sm += psum[((size_t)b * nch + c) * HF + f];
    }
    out[b * 256 + f] = mx;
    out[b * 256 + 128 + f] = sm / (float)n;
}

// final MLP + log_softmax, one block per batch element
__global__ __launch_bounds__(256) void mlp_kernel(const float* __restrict__ x1,
                                                  const float* __restrict__ x2,
                                                  const float* __restrict__ x3,
                                                  const float* __restrict__ Wl1,
                                                  const float* __restrict__ bl1,
                                                  const float* __restrict__ Wl2,
                                                  const float* __restrict__ bl2,
                                                  const float* __restrict__ Wl3,
                                                  const float* __restrict__ bl3,
                                                  float* __restrict__ out) {
    __shared__ float z[256];
    __shared__ float h1[128];
    __shared__ float h2[64];
    __shared__ float o[NC];
    int b = blockIdx.x;
    int t = threadIdx.x;
    z[t] = fmaxf(x1[b * 256 + t], 0.f) + fmaxf(x2[b * 256 + t], 0.f) + fmaxf(x3[b * 256 + t], 0.f);
    __syncthreads();
    if (t < 128) {
        float acc = bl1[t];
        for (int k = 0; k < 256; k++) acc += z[k] * Wl1[k * 128 + t];
        h1[t] = fmaxf(acc, 0.f);
    }
    __syncthreads();
    if (t < 64) {
        float acc = bl2[t];
        for (int k = 0; k < 128; k++) acc += h1[k] * Wl2[k * 64 + t];
        h2[t] = fmaxf(acc, 0.f);
    }
    __syncthreads();
    if (t < NC) {
        float acc = bl3[t];
        for (int k = 0; k < 64; k++) acc += h2[k] * Wl3[k * NC + t];
        o[t] = acc;
    }
    __syncthreads();
    if (t == 0) {
        float mx = o[0];
        for (int c = 1; c < NC; c++) mx = fmaxf(mx, o[c]);
        float s = 0.f;
        for (int c = 0; c < NC; c++) s += expf(o[c] - mx);
        float lse = mx + logf(s);
        for (int c = 0; c < NC; c++) out[b * NC + c] = o[c] - lse;
    }
}

extern "C" void kernel_launch(void* const* d_in, const int* in_sizes, int n_in,
                              void* d_out, int out_size, void* d_ws, size_t ws_size,
                              hipStream_t stream) {
    const float* x    = (const float*)d_in[0];
    const float* adj  = (const float*)d_in[1];
    const float* W1   = (const float*)d_in[2];
    const float* b1   = (const float*)d_in[3];
    const float* att1 = (const float*)d_in[4];
    const float* W2   = (const float*)d_in[5];
    const float* b2   = (const float*)d_in[6];
    const float* att2 = (const float*)d_in[7];
    const float* W3   = (const float*)d_in[8];
    const float* b3   = (const float*)d_in[9];
    const float* Wl1  = (const float*)d_in[10];
    const float* bl1  = (const float*)d_in[11];
    const float* Wl2  = (const float*)d_in[12];
    const float* bl2  = (const float*)d_in[13];
    const float* Wl3  = (const float*)d_in[14];
    const float* bl3  = (const float*)d_in[15];
    float* out = (float*)d_out;

    char* wp = (char*)d_ws;
    auto allocf = [&](size_t n) { float* r = (float*)wp; wp += n * sizeof(float); return r; };
    auto alloci = [&](size_t n) { int* r = (int*)wp; wp += n * sizeof(int); return r; };
    auto allocu = [&](size_t n) { unsigned* r = (unsigned*)wp; wp += n * sizeof(unsigned); return r; };

    float* dinvg1    = allocf(BB * N1);
    float* dinvi1    = allocf(BB * N1);
    float* hw        = allocf((size_t)BB * N1 * HF);   // shared GEMM scratch (max size)
    float* h1        = allocf((size_t)BB * N1 * HF);
    float* score1    = allocf(BB * N1);
    int*   perm1     = alloci(BB * K1);
    float* xp1       = allocf((size_t)BB * K1 * HF);
    unsigned* bitsA  = allocu((size_t)BB * N1 * 16);
    unsigned* bitsB  = allocu((size_t)BB * N1 * 16);
    float* adjval    = allocf((size_t)BB * N1 * N1);   // CSR values -> coef_info (in-place)
    float* coefg     = allocf((size_t)BB * N1 * N1);   // gcn coefs (augmented slots)
    float* ai1       = allocf(BB * K1);
    float* aj1       = allocf(BB * K1);
    float* adj1      = allocf((size_t)BB * K1 * K1);
    float* x1r       = allocf(BB * 256);
    float* dinvg2    = allocf(BB * K1);
    float* dinvi2    = allocf(BB * K1);
    float* h2        = allocf((size_t)BB * K1 * HF);
    float* score2    = allocf(BB * K1);
    int*   perm2     = alloci(BB * K2);
    float* xp2       = allocf((size_t)BB * K2 * HF);
    float* ai2       = allocf(BB * K2);
    float* aj2       = allocf(BB * K2);
    float* adj2      = allocf((size_t)BB * K2 * K2);
    float* x2r       = allocf(BB * 256);
    float* dinvg3    = allocf(BB * K2);
    float* dinvi3    = allocf(BB * K2);
    float* h3        = allocf((size_t)BB * K2 * HF);
    float* x3r       = allocf(BB * 256);
    float* pmax      = allocf((size_t)BB * 8 * HF);    // readout partials (max nch=8)
    float* psum      = allocf((size_t)BB * 8 * HF);

    // ---------------- Stage 1 (n=512 -> K1=256) ----------------
    deg_bits_kernel<<<dim3(BB * N1), dim3(64), 0, stream>>>(adj, dinvg1, dinvi1, bitsA, adjval, N1);
    build_coef<<<dim3(BB * N1 / 4), dim3(256), 0, stream>>>(bitsA, adjval, coefg, dinvg1, dinvi1, N1);
    gemm128<<<dim3(BB * N1 / 16), dim3(128), 0, stream>>>(x, W1, hw, BB * N1);
    gcn_agg<<<dim3(BB * N1), dim3(128), 0, stream>>>(coefg, bitsA, dinvg1, hw, b1, h1, N1);
    info_score<<<dim3(BB * N1), dim3(128), 0, stream>>>(adjval, bitsA, dinvi1, h1, score1, N1);
    topk_kernel<512><<<dim3(BB), dim3(512), 0, stream>>>(score1, perm1, K1);
    gather_rows<<<dim3(BB * K1), dim3(128), 0, stream>>>(h1, perm1, xp1, N1, K1);
    bits_expand<<<dim3(BB * N1), dim3(64), 0, stream>>>(bitsA, bitsB, N1, 16);          // s -> s2 (all rows)
    bits_expand_perm<<<dim3(BB * K1), dim3(64), 0, stream>>>(bitsB, perm1, bitsA, N1, 16, K1); // s2 -> s4 (perm rows)
    attn_dots<<<dim3(BB * K1), dim3(128), 0, stream>>>(xp1, att1, ai1, aj1);
    sparsemax_wave<K1><<<dim3(BB * K1 / 4), dim3(256), 0, stream>>>(ai1, aj1, perm1, adj, bitsA, adj1, N1, 16);
    readout_partial<<<dim3(BB * (K1 / 32)), dim3(128), 0, stream>>>(xp1, pmax, psum, K1, K1 / 32);
    readout_combine<<<dim3(BB), dim3(128), 0, stream>>>(pmax, psum, x1r, K1, K1 / 32);

    // ---------------- Stage 2 (n=256 -> K2=128) ----------------
    deg_bits_kernel<<<dim3(BB * K1), dim3(64), 0, stream>>>(adj1, dinvg2, dinvi2, bitsA, adjval, K1);
    build_coef<<<dim3(BB * K1 / 4), dim3(256), 0, stream>>>(bitsA, adjval, coefg, dinvg2, dinvi2, K1);
    gemm128<<<dim3(BB * K1 / 16), dim3(128), 0, stream>>>(xp1, W2, hw, BB * K1);
    gcn_agg<<<dim3(BB * K1), dim3(128), 0, stream>>>(coefg, bitsA, dinvg2, hw, b2, h2, K1);
    info_score<<<dim3(BB * K1), dim3(128), 0, stream>>>(adjval, bitsA, dinvi2, h2, score2, K1);
    topk_kernel<256><<<dim3(BB), dim3(256), 0, stream>>>(score2, perm2, K2);
    gather_rows<<<dim3(BB * K2), dim3(128), 0, stream>>>(h2, perm2, xp2, K1, K2);
    bits_expand<<<dim3(BB * K1), dim3(64), 0, stream>>>(bitsA, bitsB, K1, 8);           // s -> s2 (all rows)
    bits_expand_perm<<<dim3(BB * K2), dim3(64), 0, stream>>>(bitsB, perm2, bitsA, K1, 8, K2); // s2 -> s4 (perm rows)
    attn_dots<<<dim3(BB * K2), dim3(128), 0, stream>>>(xp2, att2, ai2, aj2);
    sparsemax_wave<K2><<<dim3(BB * K2 / 4), dim3(256), 0, stream>>>(ai2, aj2, perm2, adj1, bitsA, adj2, K1, 8);
    readout_partial<<<dim3(BB * (K2 / 32)), dim3(128), 0, stream>>>(xp2, pmax, psum, K2, K2 / 32);
    readout_combine<<<dim3(BB), dim3(128), 0, stream>>>(pmax, psum, x2r, K2, K2 / 32);

    // ---------------- Stage 3 (GCN on adj2) ----------------
    deg_bits_kernel<<<dim3(BB * K2), dim3(64), 0, stream>>>(adj2, dinvg3, dinvi3, bitsB, adjval, K2);
    build_coef<<<dim3(BB * K2 / 4), dim3(256), 0, stream>>>(bitsB, adjval, coefg, dinvg3, dinvi3, K2);
    gemm128<<<dim3(BB * K2 / 16), dim3(128), 0, stream>>>(xp2, W3, hw, BB * K2);
    gcn_agg<<<dim3(BB * K2), dim3(128), 0, stream>>>(coefg, bitsB, dinvg3, hw, b3, h3, K2);
    readout_partial<<<dim3(BB * (K2 / 32)), dim3(128), 0, stream>>>(h3, pmax, psum, K2, K2 / 32);
    readout_combine<<<dim3(BB), dim3(128), 0, stream>>>(pmax, psum, x3r, K2, K2 / 32);

    // ---------------- Final MLP ----------------
    mlp_kernel<<<dim3(BB), dim3(256), 0, stream>>>(x1r, x2r, x3r, Wl1, bl1, Wl2, bl2, Wl3, bl3, out);
}

// Round 13
// 470.649 us; speedup vs baseline: 1.1075x; 1.1075x over previous
//
#include <hip/hip_runtime.h>
#include <math.h>

#define BB 64
#define N1 512
#define K1 256
#define K2 128
#define HF 128   // feature dim
#define NC 10

// XCD-aware bijective swizzle: contiguous 1/8 chunks of the grid per XCD.
__device__ __forceinline__ int xcd_swizzle(int bid, int nwg) {
    return (bid & 7) * (nwg >> 3) + (bid >> 3);
}

// ---------------------------------------------------------------------------
// degree + bitset + CSR-value kernel: one wave per row.
// Writes dinv (= deg>0 ? 1/sqrt(deg) : 0) directly.
// ---------------------------------------------------------------------------
__global__ __launch_bounds__(64) void deg_bits_kernel(const float* __restrict__ adj,
                                                      float* __restrict__ dinv_gcn,
                                                      float* __restrict__ dinv_info,
                                                      unsigned* __restrict__ bits,
                                                      float* __restrict__ adjval, int n) {
    int row = blockIdx.x;              // b*n + i
    int i = row % n;
    const float* ar = adj + (size_t)row * n;
    float* av = adjval + (size_t)row * n;
    int lane = threadIdx.x;            // 64
    int W = n >> 5;
    unsigned* wrow = bits + (size_t)row * W;
    float s = 0.f;
    int base = 0;
    int kn = n >> 6;
    for (int k = 0; k < kn; k++) {
        float a = ar[k * 64 + lane];
        s += a;
        unsigned long long m = __ballot(a > 0.f);
        if (lane == 0) {
            wrow[2 * k]     = (unsigned)(m & 0xffffffffull);
            wrow[2 * k + 1] = (unsigned)(m >> 32);
        }
        if (a > 0.f) {
            int slot = base + (int)__popcll(m & ((1ull << lane) - 1ull));
            av[slot] = a;
        }
        base += (int)__popcll(m);
    }
    for (int off = 32; off > 0; off >>= 1) s += __shfl_down(s, off);
    if (lane == 0) {
        float diag = ar[i];
        float dg = s + (diag == 0.f ? 1.f : 0.f);
        dinv_info[row] = s  > 0.f ? 1.f / sqrtf(s)  : 0.f;
        dinv_gcn[row]  = dg > 0.f ? 1.f / sqrtf(dg) : 0.f;
    }
}

// ---------------------------------------------------------------------------
// Y[M,128] = X[M,128] @ W[128,128].
// ---------------------------------------------------------------------------
__global__ __launch_bounds__(128) void gemm128(const float* __restrict__ X,
                                               const float* __restrict__ W,
                                               float* __restrict__ Y, int M) {
    __shared__ float xl[16 * 128];
    int f = threadIdx.x;
    int r0 = blockIdx.x * 16;
    for (int idx = f; idx < 16 * 128; idx += 128) {
        int r = idx >> 7, k = idx & 127;
        xl[idx] = X[(size_t)(r0 + r) * 128 + k];
    }
    __syncthreads();
    float acc[16];
#pragma unroll
    for (int r = 0; r < 16; r++) acc[r] = 0.f;
    for (int k = 0; k < 128; k++) {
        float w = W[k * 128 + f];
#pragma unroll
        for (int r = 0; r < 16; r++) acc[r] += xl[r * 128 + k] * w;
    }
#pragma unroll
    for (int r = 0; r < 16; r++) Y[(size_t)(r0 + r) * 128 + f] = acc[r];
}

// ---------------------------------------------------------------------------
// gcn_agg: 4 rows / 256-thr block; wave w owns row w (setup + gather).
// 64 lanes x float2 over 128 features: 1 addr + 1 load per 2 FMAs.
// Per-feature accumulation order identical to prior rounds (bit-exact).
// ---------------------------------------------------------------------------
__global__ __launch_bounds__(256) void gcn_agg(const float* __restrict__ adjval,
                                               const unsigned* __restrict__ bits,
                                               const float* __restrict__ dinvg,
                                               const float* __restrict__ hin,
                                               const float* __restrict__ bias,
                                               float* __restrict__ hout, int n) {
    __shared__ int idxl[4][512];
    __shared__ float coef[4][512];
    int blk = xcd_swizzle(blockIdx.x, gridDim.x);
    int wid = threadIdx.x >> 6;
    int lane = threadIdx.x & 63;
    int row = blk * 4 + wid;
    int b = row / n, i = row % n;
    int W = n >> 5;
    const float* avrow = adjval + (size_t)row * n;
    const float* dg = dinvg + b * n;
    // wave-local setup: packed scan (augmented count | original count)
    unsigned worig = (lane < W) ? bits[(size_t)row * W + lane] : 0u;
    unsigned w = worig;
    if ((i >> 5) == lane) w |= (1u << (i & 31));     // ensure self bit
    int pca = __popc(w), pco = __popc(worig);
    int sc = (pca << 16) | pco;
#pragma unroll
    for (int off = 1; off < 64; off <<= 1) {
        int t = __shfl_up(sc, off);
        if (lane >= off) sc += t;
    }
    int nnz = __shfl(sc, 63) >> 16;
    int o  = (sc >> 16) - pca;
    int cb = (sc & 0xffff) - pco;
    unsigned mm = w;
    while (mm) {
        int bp = __ffs(mm) - 1;
        mm &= mm - 1;
        int j = (lane << 5) + bp;
        float a = ((worig >> bp) & 1u) ? avrow[cb++] : 1.f;   // inserted self = 1
        idxl[wid][o] = j;
        coef[wid][o] = a * dg[j];
        o++;
    }
    __syncthreads();
    const float* hf = hin + (size_t)b * n * HF + 2 * lane;
    float ax = 0.f, ay = 0.f;
    int it = 0;
    for (; it + 4 <= nnz; it += 4) {
        int j0 = idxl[wid][it], j1 = idxl[wid][it + 1], j2 = idxl[wid][it + 2], j3 = idxl[wid][it + 3];
        float2 v0 = *(const float2*)(hf + (size_t)j0 * HF);
        float2 v1 = *(const float2*)(hf + (size_t)j1 * HF);
        float2 v2 = *(const float2*)(hf + (size_t)j2 * HF);
        float2 v3 = *(const float2*)(hf + (size_t)j3 * HF);
        float c0 = coef[wid][it], c1 = coef[wid][it + 1], c2 = coef[wid][it + 2], c3 = coef[wid][it + 3];
        ax += c0 * v0.x; ay += c0 * v0.y;
        ax += c1 * v1.x; ay += c1 * v1.y;
        ax += c2 * v2.x; ay += c2 * v2.y;
        ax += c3 * v3.x; ay += c3 * v3.y;
    }
    for (; it < nnz; it++) {
        int j = idxl[wid][it];
        float c = coef[wid][it];
        float2 v = *(const float2*)(hf + (size_t)j * HF);
        ax += c * v.x; ay += c * v.y;
    }
    float di = dg[i];
    float bx = bias[2 * lane], by = bias[2 * lane + 1];
    float2 outv = make_float2(fmaxf(di * ax + bx, 0.f), fmaxf(di * ay + by, 0.f));
    *(float2*)(hout + (size_t)row * HF + 2 * lane) = outv;
}

__global__ __launch_bounds__(256) void info_score(const float* __restrict__ adjval,
                                                  const unsigned* __restrict__ bits,
                                                  const float* __restrict__ dinvi,
                                                  const float* __restrict__ h,
                                                  float* __restrict__ score, int n) {
    __shared__ int idxl[4][512];
    __shared__ float coef[4][512];
    int blk = xcd_swizzle(blockIdx.x, gridDim.x);
    int wid = threadIdx.x >> 6;
    int lane = threadIdx.x & 63;
    int row = blk * 4 + wid;
    int b = row / n, i = row % n;
    int W = n >> 5;
    const float* avrow = adjval + (size_t)row * n;
    const float* di_ = dinvi + b * n;
    unsigned w = (lane < W) ? bits[(size_t)row * W + lane] : 0u;
    int pc = __popc(w);
    int sc = pc;
#pragma unroll
    for (int off = 1; off < 64; off <<= 1) {
        int t = __shfl_up(sc, off);
        if (lane >= off) sc += t;
    }
    int nnz = __shfl(sc, 63);
    int o = sc - pc;                   // == CSR slot (no augmentation)
    unsigned mm = w;
    while (mm) {
        int bp = __ffs(mm) - 1;
        mm &= mm - 1;
        int j = (lane << 5) + bp;
        idxl[wid][o] = j;
        coef[wid][o] = avrow[o] * di_[j];
        o++;
    }
    __syncthreads();
    const float* hf = h + (size_t)b * n * HF + 2 * lane;
    float ax = 0.f, ay = 0.f;
    int it = 0;
    for (; it + 4 <= nnz; it += 4) {
        int j0 = idxl[wid][it], j1 = idxl[wid][it + 1], j2 = idxl[wid][it + 2], j3 = idxl[wid][it + 3];
        float2 v0 = *(const float2*)(hf + (size_t)j0 * HF);
        float2 v1 = *(const float2*)(hf + (size_t)j1 * HF);
        float2 v2 = *(const float2*)(hf + (size_t)j2 * HF);
        float2 v3 = *(const float2*)(hf + (size_t)j3 * HF);
        float c0 = coef[wid][it], c1 = coef[wid][it + 1], c2 = coef[wid][it + 2], c3 = coef[wid][it + 3];
        ax += c0 * v0.x; ay += c0 * v0.y;
        ax += c1 * v1.x; ay += c1 * v1.y;
        ax += c2 * v2.x; ay += c2 * v2.y;
        ax += c3 * v3.x; ay += c3 * v3.y;
    }
    for (; it < nnz; it++) {
        int j = idxl[wid][it];
        float c = coef[wid][it];
        float2 v = *(const float2*)(hf + (size_t)j * HF);
        ax += c * v.x; ay += c * v.y;
    }
    float dii = di_[i];
    float2 hself = *(const float2*)(hf + (size_t)i * HF);
    float r = fabsf(hself.x - dii * ax) + fabsf(hself.y - dii * ay);
#pragma unroll
    for (int off = 1; off < 64; off <<= 1) r += __shfl_xor(r, off);
    if (lane == 0) score[row] = r;
}

// ---------------------------------------------------------------------------
// top-k: per-graph bitonic sort on 64-bit key.
// ---------------------------------------------------------------------------
template <int NN>
__global__ __launch_bounds__(NN) void topk_kernel(const float* __restrict__ score,
                                                  int* __restrict__ perm, int k) {
    __shared__ unsigned long long keys[NN];
    int b = blockIdx.x, t = threadIdx.x;
    unsigned u = __float_as_uint(score[b * NN + t]);
    unsigned asc = (u & 0x80000000u) ? ~u : (u | 0x80000000u); // monotone map
    unsigned desc = ~asc;                                      // larger score -> smaller key
    keys[t] = ((unsigned long long)desc << 32) | (unsigned)t;
    __syncthreads();
    for (int kk = 2; kk <= NN; kk <<= 1) {
        for (int j = kk >> 1; j > 0; j >>= 1) {
            int ixj = t ^ j;
            if (ixj > t) {
                bool up = ((t & kk) == 0);
                unsigned long long a = keys[t], c = keys[ixj];
                if ((a > c) == up) { keys[t] = c; keys[ixj] = a; }
            }
            __syncthreads();
        }
    }
    if (t < k) perm[b * k + t] = (int)(keys[t] & 0xffffffffu);
}

__global__ __launch_bounds__(128) void gather_rows(const float* __restrict__ h,
                                                   const int* __restrict__ perm,
                                                   float* __restrict__ xp, int n, int k) {
    int idx = blockIdx.x;  // b*k + i
    int b = idx / k;
    int f = threadIdx.x;
    int pi = perm[idx];
    xp[(size_t)idx * HF + f] = h[((size_t)b * n + pi) * HF + f];
}

// ---------------------------------------------------------------------------
// bits expansion pass 1 (all rows).
// ---------------------------------------------------------------------------
__global__ __launch_bounds__(64) void bits_expand(const unsigned* __restrict__ sin,
                                                  unsigned* __restrict__ sout, int n, int W) {
    __shared__ unsigned rowi[16];
    __shared__ int jlist[512];
    __shared__ unsigned res[64];
    __shared__ int s_nnz;
    int row = blockIdx.x;
    int b = row / n;
    int t = threadIdx.x;       // 64
    unsigned w = (t < W) ? sin[(size_t)row * W + t] : 0u;
    if (t < W) rowi[t] = w;
    int pc = __popc(w);
    int sc = pc;
#pragma unroll
    for (int off = 1; off < 64; off <<= 1) {
        int v = __shfl_up(sc, off);
        if (t >= off) sc += v;
    }
    if (t == 63) s_nnz = sc;
    int o = sc - pc;
    unsigned mm = w;
    while (mm) {
        int bp = __ffs(mm) - 1;
        mm &= mm - 1;
        jlist[o++] = (t << 5) + bp;
    }
    __syncthreads();
    int nnz = s_nnz;
    int JC = 64 / W;
    int chunk = t / W, wi = t % W;
    const unsigned* sb = sin + (size_t)b * n * W;
    unsigned r = 0;
    int q = chunk;
    for (; q + 3 * JC < nnz; q += 4 * JC) {
        int j0 = jlist[q], j1 = jlist[q + JC], j2 = jlist[q + 2 * JC], j3 = jlist[q + 3 * JC];
        unsigned v0 = sb[(size_t)j0 * W + wi];
        unsigned v1 = sb[(size_t)j1 * W + wi];
        unsigned v2 = sb[(size_t)j2 * W + wi];
        unsigned v3 = sb[(size_t)j3 * W + wi];
        r |= v0 | v1 | v2 | v3;
    }
    for (; q < nnz; q += JC) r |= sb[(size_t)jlist[q] * W + wi];
    res[t] = r;
    __syncthreads();
    if (t < W) {
        unsigned acc = rowi[t];
        for (int c = 0; c < JC; c++) acc |= res[c * W + t];
        sout[(size_t)row * W + t] = acc;
    }
}

// ---------------------------------------------------------------------------
// bits expansion pass 2, perm-compacted.
// ---------------------------------------------------------------------------
__global__ __launch_bounds__(64) void bits_expand_perm(const unsigned* __restrict__ sin,
                                                       const int* __restrict__ perm,
                                                       unsigned* __restrict__ sout,
                                                       int n, int W, int k) {
    __shared__ unsigned rowi[16];
    __shared__ int jlist[512];
    __shared__ unsigned res[64];
    __shared__ int s_nnz;
    int r0 = blockIdx.x;       // b*k + i
    int b = r0 / k;
    int pi = perm[r0];
    int t = threadIdx.x;       // 64
    size_t srow = (size_t)(b * n + pi) * W;
    unsigned w = (t < W) ? sin[srow + t] : 0u;
    if (t < W) rowi[t] = w;
    int pc = __popc(w);
    int sc = pc;
#pragma unroll
    for (int off = 1; off < 64; off <<= 1) {
        int v = __shfl_up(sc, off);
        if (t >= off) sc += v;
    }
    if (t == 63) s_nnz = sc;
    int o = sc - pc;
    unsigned mm = w;
    while (mm) {
        int bp = __ffs(mm) - 1;
        mm &= mm - 1;
        jlist[o++] = (t << 5) + bp;
    }
    __syncthreads();
    int nnz = s_nnz;
    int JC = 64 / W;
    int chunk = t / W, wi = t % W;
    const unsigned* sb = sin + (size_t)b * n * W;
    unsigned r = 0;
    int q = chunk;
    for (; q + 3 * JC < nnz; q += 4 * JC) {
        int j0 = jlist[q], j1 = jlist[q + JC], j2 = jlist[q + 2 * JC], j3 = jlist[q + 3 * JC];
        unsigned v0 = sb[(size_t)j0 * W + wi];
        unsigned v1 = sb[(size_t)j1 * W + wi];
        unsigned v2 = sb[(size_t)j2 * W + wi];
        unsigned v3 = sb[(size_t)j3 * W + wi];
        r |= v0 | v1 | v2 | v3;
    }
    for (; q < nnz; q += JC) r |= sb[(size_t)jlist[q] * W + wi];
    res[t] = r;
    __syncthreads();
    if (t < W) {
        unsigned acc = rowi[t];
        for (int c = 0; c < JC; c++) acc |= res[c * W + t];
        sout[(size_t)r0 * W + t] = acc;
    }
}

// a_i = xp.att[:128], a_j = xp.att[128:]
__global__ __launch_bounds__(128) void attn_dots(const float* __restrict__ xp,
                                                 const float* __restrict__ att,
                                                 float* __restrict__ ai, float* __restrict__ aj) {
    __shared__ float red[128];
    int idx = blockIdx.x;
    int f = threadIdx.x;
    float v = xp[(size_t)idx * HF + f];
    red[f] = v * att[f];
    __syncthreads();
    for (int s = 64; s > 0; s >>= 1) {
        if (f < s) red[f] += red[f + s];
        __syncthreads();
    }
    if (f == 0) ai[idx] = red[0];
    __syncthreads();
    red[f] = v * att[128 + f];
    __syncthreads();
    for (int s = 64; s > 0; s >>= 1) {
        if (f < s) red[f] += red[f + s];
        __syncthreads();
    }
    if (f == 0) aj[idx] = red[0];
}

// ---------------------------------------------------------------------------
// sparsemax, wave-per-row, register-resident, barrier-free.
// ---------------------------------------------------------------------------
template <int K>
__global__ __launch_bounds__(256) void sparsemax_wave(const float* __restrict__ ai,
                                                      const float* __restrict__ aj,
                                                      const int* __restrict__ perm,
                                                      const float* __restrict__ adjprev,
                                                      const unsigned* __restrict__ s4c,
                                                      float* __restrict__ newadj,
                                                      int nprev, int Wprev) {
    constexpr int EPL = K / 64;
    int lane = threadIdx.x & 63;
    int wid = threadIdx.x >> 6;
    int r = blockIdx.x * 4 + wid;      // row id: b*K + i
    int b = r / K, i = r % K;
    int pi = perm[r];
    float air = ai[r];
    const float* aprow = adjprev + ((size_t)b * nprev + pi) * nprev;
    const unsigned* srow = s4c + (size_t)r * Wprev;
    const int* permb = perm + b * K;
    const float* ajb = aj + b * K;

    float z[EPL], zc[EPL], zs[EPL];
    unsigned mbits = 0;
    float m = -1e30f;
#pragma unroll
    for (int e = 0; e < EPL; e++) {
        int j = lane * EPL + e;
        int pj = permb[j];
        float ap = aprow[pj];
        unsigned wb = srow[pj >> 5];
        bool mask = ((wb >> (pj & 31)) & 1u) || (i == j);
        float v = air + ajb[j];
        float lr = v > 0.f ? v : 0.2f * v;
        z[e] = lr + ap;                // LAMB = 1
        if (mask) mbits |= (1u << e);
        m = fmaxf(m, mask ? z[e] : -1e30f);
    }
    // wave allreduce max
#pragma unroll
    for (int off = 1; off < 64; off <<= 1) m = fmaxf(m, __shfl_xor(m, off));

#pragma unroll
    for (int e = 0; e < EPL; e++) {
        zc[e] = z[e] - m;
        zs[e] = ((mbits >> e) & 1u) ? zc[e] : -1e30f;
    }

    // bitonic sort descending over K elements
    for (int kk = 2; kk <= K; kk <<= 1) {
        for (int d = kk >> 1; d >= EPL; d >>= 1) {
            int lm = d / EPL;
#pragma unroll
            for (int e = 0; e < EPL; e++) {
                float other = __shfl_xor(zs[e], lm);
                int idx = lane * EPL + e;
                bool desc = (idx & kk) == 0;
                bool lower = (lane & lm) == 0;
                zs[e] = (desc == lower) ? fmaxf(zs[e], other) : fminf(zs[e], other);
            }
        }
#pragma unroll
        for (int dd = EPL >> 1; dd >= 1; dd >>= 1) {
            if (kk > dd) {
#pragma unroll
                for (int e = 0; e < EPL; e++) {
                    if (!(e & dd)) {
                        int ep = e | dd;
                        int idx = lane * EPL + e;
                        bool desc = (idx & kk) == 0;
                        float a = zs[e], c = zs[ep];
                        float mx = fmaxf(a, c), mn = fminf(a, c);
                        zs[e] = desc ? mx : mn;
                        zs[ep] = desc ? mn : mx;
                    }
                }
            }
        }
    }

    // inclusive cumsum: per-lane sequential + Kogge-Stone lane scan
    float c[EPL];
    c[0] = zs[0];
#pragma unroll
    for (int e = 1; e < EPL; e++) c[e] = c[e - 1] + zs[e];
    float lsum = c[EPL - 1];
    float sc = lsum;
#pragma unroll
    for (int off = 1; off < 64; off <<= 1) {
        float t = __shfl_up(sc, off);
        if (lane >= off) sc += t;
    }
    float excl = sc - lsum;
#pragma unroll
    for (int e = 0; e < EPL; e++) c[e] += excl;   // c[e] = cum at idx lane*EPL+e

    // rho = count of (1 + (idx+1)*zsort > cum)
    int cnt = 0;
#pragma unroll
    for (int e = 0; e < EPL; e++) {
        int idx = lane * EPL + e;
        if (1.f + (float)(idx + 1) * zs[e] > c[e]) cnt++;
    }
#pragma unroll
    for (int off = 1; off < 64; off <<= 1) cnt += __shfl_xor(cnt, off);
    int rho = cnt;

    // cum at index rho-1
    int pos = rho - 1;
    int tl = pos / EPL, te = pos % EPL;
    float g[EPL];
#pragma unroll
    for (int e = 0; e < EPL; e++) g[e] = __shfl(c[e], tl);
    float cum_rho = g[0];
#pragma unroll
    for (int e = 1; e < EPL; e++) cum_rho = (te == e) ? g[e] : cum_rho;
    float tau = (cum_rho - 1.f) / (float)rho;

    float o[EPL];
#pragma unroll
    for (int e = 0; e < EPL; e++)
        o[e] = fmaxf(zc[e] - tau, 0.f) * (((mbits >> e) & 1u) ? 1.f : 0.f);

    float* orow = newadj + (size_t)r * K + lane * EPL;
    if constexpr (EPL == 4) {
        *reinterpret_cast<float4*>(orow) = make_float4(o[0], o[1], o[2], o[3]);
    } else {
        *reinterpret_cast<float2*>(orow) = make_float2(o[0], o[1]);
    }
}

// ---------------------------------------------------------------------------
// readout, two-pass.
// ---------------------------------------------------------------------------
__global__ __launch_bounds__(128) void readout_partial(const float* __restrict__ h,
                                                       float* __restrict__ pmax,
                                                       float* __restrict__ psum,
                                                       int n, int nch) {
    int blk = blockIdx.x;              // b*nch + c
    int c = blk % nch;
    int f = threadIdx.x;
    const float* hb = h + ((size_t)(blk / nch) * n + c * 32) * HF;
    float mx = -INFINITY, sm = 0.f;
#pragma unroll
    for (int i = 0; i < 32; i++) {
        float v = hb[(size_t)i * HF + f];
        mx = fmaxf(mx, v);
        sm += v;
    }
    pmax[(size_t)blk * HF + f] = mx;
    psum[(size_t)blk * HF + f] = sm;
}

__global__ __launch_bounds__(128) void readout_combine(const float* __restrict__ pmax,
                                                       const float* __restrict__ psum,
                                                       float* __restrict__ out,
                                                       int n, int nch) {
    int b = blockIdx.x;
    int f = threadIdx.x;
    float mx = -INFINITY, sm = 0.f;
    for (int c = 0; c < nch; c++) {
        mx = fmaxf(mx, pmax[((size_t)b * nch + c) * HF + f]);
        sm += psum[((size_t)b * nch + c) * HF + f];
    }
    out[b * 256 + f] = mx;
    out[b * 256 + 128 + f] = sm / (float)n;
}

// final MLP + log_softmax, one block per batch element
__global__ __launch_bounds__(256) void mlp_kernel(const float* __restrict__ x1,
                                                  const float* __restrict__ x2,
                                                  const float* __restrict__ x3,
                                                  const float* __restrict__ Wl1,
                                                  const float* __restrict__ bl1,
                                                  const float* __restrict__ Wl2,
                                                  const float* __restrict__ bl2,
                                                  const float* __restrict__ Wl3,
                                                  const float* __restrict__ bl3,
                                                  float* __restrict__ out) {
    __shared__ float z[256];
    __shared__ float h1[128];
    __shared__ float h2[64];
    __shared__ float o[NC];
    int b = blockIdx.x;
    int t = threadIdx.x;
    z[t] = fmaxf(x1[b * 256 + t], 0.f) + fmaxf(x2[b * 256 + t], 0.f) + fmaxf(x3[b * 256 + t], 0.f);
    __syncthreads();
    if (t < 128) {
        float acc = bl1[t];
        for (int k = 0; k < 256; k++) acc += z[k] * Wl1[k * 128 + t];
        h1[t] = fmaxf(acc, 0.f);
    }
    __syncthreads();
    if (t < 64) {
        float acc = bl2[t];
        for (int k = 0; k < 128; k++) acc += h1[k] * Wl2[k * 64 + t];
        h2[t] = fmaxf(acc, 0.f);
    }
    __syncthreads();
    if (t < NC) {
        float acc = bl3[t];
        for (int k = 0; k < 64; k++) acc += h2[k] * Wl3[k * NC + t];
        o[t] = acc;
    }
    __syncthreads();
    if (t == 0) {
        float mx = o[0];
        for (int c = 1; c < NC; c++) mx = fmaxf(mx, o[c]);
        float s = 0.f;
        for (int c = 0; c < NC; c++) s += expf(o[c] - mx);
        float lse = mx + logf(s);
        for (int c = 0; c < NC; c++) out[b * NC + c] = o[c] - lse;
    }
}

extern "C" void kernel_launch(void* const* d_in, const int* in_sizes, int n_in,
                              void* d_out, int out_size, void* d_ws, size_t ws_size,
                              hipStream_t stream) {
    const float* x    = (const float*)d_in[0];
    const float* adj  = (const float*)d_in[1];
    const float* W1   = (const float*)d_in[2];
    const float* b1   = (const float*)d_in[3];
    const float* att1 = (const float*)d_in[4];
    const float* W2   = (const float*)d_in[5];
    const float* b2   = (const float*)d_in[6];
    const float* att2 = (const float*)d_in[7];
    const float* W3   = (const float*)d_in[8];
    const float* b3   = (const float*)d_in[9];
    const float* Wl1  = (const float*)d_in[10];
    const float* bl1  = (const float*)d_in[11];
    const float* Wl2  = (const float*)d_in[12];
    const float* bl2  = (const float*)d_in[13];
    const float* Wl3  = (const float*)d_in[14];
    const float* bl3  = (const float*)d_in[15];
    float* out = (float*)d_out;

    char* wp = (char*)d_ws;
    auto allocf = [&](size_t n) { float* r = (float*)wp; wp += n * sizeof(float); return r; };
    auto alloci = [&](size_t n) { int* r = (int*)wp; wp += n * sizeof(int); return r; };
    auto allocu = [&](size_t n) { unsigned* r = (unsigned*)wp; wp += n * sizeof(unsigned); return r; };

    float* dinvg1    = allocf(BB * N1);
    float* dinvi1    = allocf(BB * N1);
    float* hw        = allocf((size_t)BB * N1 * HF);   // shared GEMM scratch (max size)
    float* h1        = allocf((size_t)BB * N1 * HF);
    float* score1    = allocf(BB * N1);
    int*   perm1     = alloci(BB * K1);
    float* xp1       = allocf((size_t)BB * K1 * HF);
    unsigned* bitsA  = allocu((size_t)BB * N1 * 16);
    unsigned* bitsB  = allocu((size_t)BB * N1 * 16);
    float* adjval    = allocf((size_t)BB * N1 * N1);   // CSR values, reused all stages
    float* ai1       = allocf(BB * K1);
    float* aj1       = allocf(BB * K1);
    float* adj1      = allocf((size_t)BB * K1 * K1);
    float* x1r       = allocf(BB * 256);
    float* dinvg2    = allocf(BB * K1);
    float* dinvi2    = allocf(BB * K1);
    float* h2        = allocf((size_t)BB * K1 * HF);
    float* score2    = allocf(BB * K1);
    int*   perm2     = alloci(BB * K2);
    float* xp2       = allocf((size_t)BB * K2 * HF);
    float* ai2       = allocf(BB * K2);
    float* aj2       = allocf(BB * K2);
    float* adj2      = allocf((size_t)BB * K2 * K2);
    float* x2r       = allocf(BB * 256);
    float* dinvg3    = allocf(BB * K2);
    float* dinvi3    = allocf(BB * K2);
    float* h3        = allocf((size_t)BB * K2 * HF);
    float* x3r       = allocf(BB * 256);
    float* pmax      = allocf((size_t)BB * 8 * HF);    // readout partials (max nch=8)
    float* psum      = allocf((size_t)BB * 8 * HF);

    // ---------------- Stage 1 (n=512 -> K1=256) ----------------
    deg_bits_kernel<<<dim3(BB * N1), dim3(64), 0, stream>>>(adj, dinvg1, dinvi1, bitsA, adjval, N1);
    gemm128<<<dim3(BB * N1 / 16), dim3(128), 0, stream>>>(x, W1, hw, BB * N1);
    gcn_agg<<<dim3(BB * N1 / 4), dim3(256), 0, stream>>>(adjval, bitsA, dinvg1, hw, b1, h1, N1);
    info_score<<<dim3(BB * N1 / 4), dim3(256), 0, stream>>>(adjval, bitsA, dinvi1, h1, score1, N1);
    topk_kernel<512><<<dim3(BB), dim3(512), 0, stream>>>(score1, perm1, K1);
    gather_rows<<<dim3(BB * K1), dim3(128), 0, stream>>>(h1, perm1, xp1, N1, K1);
    bits_expand<<<dim3(BB * N1), dim3(64), 0, stream>>>(bitsA, bitsB, N1, 16);          // s -> s2 (all rows)
    bits_expand_perm<<<dim3(BB * K1), dim3(64), 0, stream>>>(bitsB, perm1, bitsA, N1, 16, K1); // s2 -> s4 (perm rows)
    attn_dots<<<dim3(BB * K1), dim3(128), 0, stream>>>(xp1, att1, ai1, aj1);
    sparsemax_wave<K1><<<dim3(BB * K1 / 4), dim3(256), 0, stream>>>(ai1, aj1, perm1, adj, bitsA, adj1, N1, 16);
    readout_partial<<<dim3(BB * (K1 / 32)), dim3(128), 0, stream>>>(xp1, pmax, psum, K1, K1 / 32);
    readout_combine<<<dim3(BB), dim3(128), 0, stream>>>(pmax, psum, x1r, K1, K1 / 32);

    // ---------------- Stage 2 (n=256 -> K2=128) ----------------
    deg_bits_kernel<<<dim3(BB * K1), dim3(64), 0, stream>>>(adj1, dinvg2, dinvi2, bitsA, adjval, K1);
    gemm128<<<dim3(BB * K1 / 16), dim3(128), 0, stream>>>(xp1, W2, hw, BB * K1);
    gcn_agg<<<dim3(BB * K1 / 4), dim3(256), 0, stream>>>(adjval, bitsA, dinvg2, hw, b2, h2, K1);
    info_score<<<dim3(BB * K1 / 4), dim3(256), 0, stream>>>(adjval, bitsA, dinvi2, h2, score2, K1);
    topk_kernel<256><<<dim3(BB), dim3(256), 0, stream>>>(score2, perm2, K2);
    gather_rows<<<dim3(BB * K2), dim3(128), 0, stream>>>(h2, perm2, xp2, K1, K2);
    bits_expand<<<dim3(BB * K1), dim3(64), 0, stream>>>(bitsA, bitsB, K1, 8);           // s -> s2 (all rows)
    bits_expand_perm<<<dim3(BB * K2), dim3(64), 0, stream>>>(bitsB, perm2, bitsA, K1, 8, K2); // s2 -> s4 (perm rows)
    attn_dots<<<dim3(BB * K2), dim3(128), 0, stream>>>(xp2, att2, ai2, aj2);
    sparsemax_wave<K2><<<dim3(BB * K2 / 4), dim3(256), 0, stream>>>(ai2, aj2, perm2, adj1, bitsA, adj2, K1, 8);
    readout_partial<<<dim3(BB * (K2 / 32)), dim3(128), 0, stream>>>(xp2, pmax, psum, K2, K2 / 32);
    readout_combine<<<dim3(BB), dim3(128), 0, stream>>>(pmax, psum, x2r, K2, K2 / 32);

    // ---------------- Stage 3 (GCN on adj2) ----------------
    deg_bits_kernel<<<dim3(BB * K2), dim3(64), 0, stream>>>(adj2, dinvg3, dinvi3, bitsB, adjval, K2);
    gemm128<<<dim3(BB * K2 / 16), dim3(128), 0, stream>>>(xp2, W3, hw, BB * K2);
    gcn_agg<<<dim3(BB * K2 / 4), dim3(256), 0, stream>>>(adjval, bitsB, dinvg3, hw, b3, h3, K2);
    readout_partial<<<dim3(BB * (K2 / 32)), dim3(128), 0, stream>>>(h3, pmax, psum, K2, K2 / 32);
    readout_combine<<<dim3(BB), dim3(128), 0, stream>>>(pmax, psum, x3r, K2, K2 / 32);

    // ---------------- Final MLP ----------------
    mlp_kernel<<<dim3(BB), dim3(256), 0, stream>>>(x1r, x2r, x3r, Wl1, bl1, Wl2, bl2, Wl3, bl3, out);
}